// Round 10
// baseline (1485.580 us; speedup 1.0000x reference)
//
#include <hip/hip_runtime.h>
#include <hip/hip_bf16.h>

typedef float f32x4 __attribute__((ext_vector_type(4)));
typedef __bf16 bf16x8 __attribute__((ext_vector_type(8)));

#define AS1 __attribute__((address_space(1)))
#define AS3 __attribute__((address_space(3)))

__device__ __forceinline__ void gload16(const void* g, void* l) {
    __builtin_amdgcn_global_load_lds((AS1 unsigned int*)g, (AS3 unsigned int*)l, 16, 0, 0);
}

__device__ __forceinline__ float bfu(unsigned short u) {
    return __uint_as_float((unsigned)u << 16);
}

// ---------------- weight prep (both conv2/conv3): OIHW f32 -> [kyx][icg][nblk][oc128][ic32] bf16 ----------------
__global__ __launch_bounds__(256) void prep_w_kernel(const float* __restrict__ wA,
                                                     const float* __restrict__ wB,
                                                     __hip_bfloat16* __restrict__ wpA,
                                                     __hip_bfloat16* __restrict__ wpB) {
    __shared__ float wl[4 * 32 * 81];  // [o][i][kyx]
    int bid = blockIdx.x;
    const float* w = (bid < 512) ? wA : wB;
    __hip_bfloat16* wp = (bid < 512) ? wpA : wpB;
    bid &= 511;
    int icg = bid & 7;
    int oc4 = (bid >> 3) & 31;
    int nblk = bid >> 8;
    int t = threadIdx.x;
    int ocg0 = nblk * 128 + oc4 * 4;
    int ic0 = icg * 32;
    for (int f = t; f < 4 * 2592; f += 256) {
        int o = f / 2592;
        int rest = f - o * 2592;  // i*81 + kyx
        wl[f] = w[(ocg0 + o) * 20736 + ic0 * 81 + rest];
    }
    __syncthreads();
    for (int idx = t; idx < 81 * 128; idx += 256) {
        int kyx = idx >> 7;
        int o = (idx >> 5) & 3;
        int i = idx & 31;
        long dst = (long)(((kyx * 8 + icg) * 2 + nblk) * 128 + (oc4 * 4 + o)) * 32 + i;
        wp[dst] = __float2bfloat16(wl[o * 2592 + i * 81 + kyx]);
    }
}

// ---------------- conv1: 1->256ch 9x9 s1, f32 compute, weights preloaded to VGPRs ----------------
__global__ __launch_bounds__(256) void conv1_kernel(const float* __restrict__ x,
                                                    const float* __restrict__ w,
                                                    const float* __restrict__ bias,
                                                    __hip_bfloat16* __restrict__ out) {
    __shared__ float rowb[504];  // 9 rows x 56
    int oy = blockIdx.x;  // 0..47
    int b = blockIdx.y;   // 0..127
    int t = threadIdx.x;  // = oc
    const float* src = x + b * 3136 + oy * 56;
    for (int i = t; i < 504; i += 256) rowb[i] = src[i];
    float w81[81];
    const float* wt = w + t * 81;
#pragma unroll
    for (int k = 0; k < 81; ++k) w81[k] = wt[k];
    __syncthreads();
    float bs = bias[t];
    __hip_bfloat16* op = out + ((b * 48 + oy) * 48) * 256 + t;
    for (int p = 0; p < 3; ++p) {
        int ox0 = p * 16;
        float acc[16];
#pragma unroll
        for (int i = 0; i < 16; ++i) acc[i] = 0.f;
#pragma unroll
        for (int ky = 0; ky < 9; ++ky) {
            float r[24];
#pragma unroll
            for (int i = 0; i < 24; ++i) r[i] = rowb[ky * 56 + ox0 + i];
#pragma unroll
            for (int kx = 0; kx < 9; ++kx) {
                float wv = w81[ky * 9 + kx];
#pragma unroll
                for (int ox = 0; ox < 16; ++ox) acc[ox] = fmaf(wv, r[ox + kx], acc[ox]);
            }
        }
#pragma unroll
        for (int ox = 0; ox < 16; ++ox) {
            float v = acc[ox] + bs;
            v = v > 0.f ? v : 0.f;
            op[(ox0 + ox) * 256] = __float2bfloat16(v);
        }
    }
}

// ---------------- conv2: one image/block, LDS-resident im2col slice, barrier-free K-loop,
// register-double-buffered A-fragments (prefetch d=1), B double-buffer (per-icg reset),
// s_sleep wave skew to anti-correlate co-resident waves. ----------------
__global__ __launch_bounds__(512, 2) void conv2_img_kernel(const __hip_bfloat16* __restrict__ in,
                                                           const __hip_bfloat16* __restrict__ wp,
                                                           const float* __restrict__ bias,
                                                           __hip_bfloat16* __restrict__ out) {
    __shared__ __hip_bfloat16 Ald[73728];   // 147456 B = [48][48][32] swizzled
    int bid = blockIdx.x;
    int wg = (bid & 7) * 32 + (bid >> 3);   // XCD-chunk: nblk pair lands on same XCD
    int b = wg >> 1, nblk = wg & 1;
    int t = threadIdx.x;
    int lane = t & 63, wid = t >> 6;
    int wr = wid >> 1, wc = wid & 1;        // 4 (M) x 2 (N) wave grid
    int ch8 = lane >> 4;

    const __hip_bfloat16* imgbase = in + (long)b * (48 * 48 * 256);
    const __hip_bfloat16* wpn = wp + (long)nblk * 4096 + (wc * 64 + (lane & 15)) * 32 + ch8 * 8;

    int qbase[7];
#pragma unroll
    for (int mi = 0; mi < 7; ++mi) {
        int ml = wr * 96 + mi * 16 + (lane & 15);
        int oy = ml / 20, ox = ml - oy * 20;
        qbase[mi] = ((2 * oy) * 48 + 2 * ox) * 4 + ch8;
    }

    f32x4 acc[7][4];
#pragma unroll
    for (int i = 0; i < 7; ++i)
#pragma unroll
        for (int j = 0; j < 4; ++j) acc[i][j] = (f32x4){0.f, 0.f, 0.f, 0.f};

    auto stageA = [&](int icg) {
#pragma unroll
        for (int c = 0; c < 3; ++c) {
            uint4 v[6];
#pragma unroll
            for (int j = 0; j < 6; ++j) {
                int gi = t + (c * 6 + j) * 512;
                int lrow = gi >> 2;
                int iy = lrow / 48;
                int col = lrow - iy * 48;
                if (iy > 46) iy = 46;  // row 47 pad, never read
                v[j] = *(const uint4*)(imgbase + (iy * 48 + col) * 256 + icg * 32 + (gi & 3) * 8);
            }
#pragma unroll
            for (int j = 0; j < 6; ++j) {
                int gi = t + (c * 6 + j) * 512;
                int phys = gi ^ ((gi >> 3) & 7);
                *(uint4*)((char*)Ald + phys * 16) = v[j];
            }
        }
    };

    bf16x8 af_e[7], af_o[7], Be[4], Bo[4];
    int pf_kdelta = 0, pf_kx = 0, pf_ky = 0;
    auto prefA = [&](bf16x8* af) {
#pragma unroll
        for (int mi = 0; mi < 7; ++mi) {
            int q = qbase[mi] + pf_kdelta;
            int phys = q ^ ((q >> 3) & 7);
            af[mi] = *(const bf16x8*)((const char*)Ald + phys * 16);
        }
        ++pf_kx; pf_kdelta += 4;
        if (pf_kx == 9) { pf_kx = 0; ++pf_ky; pf_kdelta = pf_ky * 192; }
    };
    auto domfma = [&](bf16x8* af, bf16x8* bf) {
        __builtin_amdgcn_s_setprio(1);
#pragma unroll
        for (int mi = 0; mi < 7; ++mi)
#pragma unroll
            for (int ni = 0; ni < 4; ++ni)
                acc[mi][ni] = __builtin_amdgcn_mfma_f32_16x16x32_bf16(af[mi], bf[ni], acc[mi][ni], 0, 0, 0);
        __builtin_amdgcn_s_setprio(0);
    };

    for (int icg = 0; icg < 8; ++icg) {
        const __hip_bfloat16* wpi = wpn + (long)icg * 8192;
        auto loadB = [&](bf16x8* dst, int kyx) {
            const __hip_bfloat16* p = wpi + (long)kyx * 65536;
#pragma unroll
            for (int ni = 0; ni < 4; ++ni) dst[ni] = *(const bf16x8*)(p + ni * 512);
        };
        if (icg) __builtin_amdgcn_s_barrier();   // all waves done reading old A
        loadB(Be, 0);
        loadB(Bo, 1);
        stageA(icg);
        asm volatile("s_waitcnt lgkmcnt(0)" ::: "memory");
        __builtin_amdgcn_s_barrier();
        if (wid >= 4) asm volatile("s_sleep 4");   // de-phase co-resident waves

        pf_kx = 0; pf_ky = 0; pf_kdelta = 0;
        prefA(af_e);                                // step 0 fragments
        for (int it2 = 0; it2 < 40; ++it2) {
            prefA(af_o);
            domfma(af_e, Be);
            loadB(Be, 2 * it2 + 2);
            prefA(af_e);
            domfma(af_o, Bo);
            loadB(Bo, 2 * it2 + 3);   // kyx 81,82 read harmless garbage past tile (never used)
        }
        domfma(af_e, Be);                           // step 80
    }

    int colbase = nblk * 128 + wc * 64 + (lane & 15);
#pragma unroll
    for (int mi = 0; mi < 7; ++mi) {
#pragma unroll
        for (int ni = 0; ni < 4; ++ni) {
            int col = colbase + ni * 16;
            float bs = bias[col];
#pragma unroll
            for (int r = 0; r < 4; ++r) {
                int ml = wr * 96 + mi * 16 + (lane >> 4) * 4 + r;
                float v = acc[mi][ni][r] + bs;
                v = v > 0.f ? v : 0.f;
                out[((long)b * 400 + ml) * 256 + col] = __float2bfloat16(v);
            }
        }
    }
}

// ---------------- conv3: implicit-GEMM 128x128 (split-K), ring-3, counted vmcnt ----------------
__global__ __launch_bounds__(256) void conv_mfma_kernel(const __hip_bfloat16* __restrict__ in,
                                                        const __hip_bfloat16* __restrict__ wp,
                                                        const float* __restrict__ bias,
                                                        __hip_bfloat16* __restrict__ out,
                                                        float* __restrict__ part,
                                                        int Win, int imgStride, int HWout, int Wout,
                                                        int nkyx, int Mtot, int mode) {
    __shared__ __hip_bfloat16 Ald[3 * 4096];
    __shared__ __hip_bfloat16 Bld[3 * 4096];
    int mblk = blockIdx.x, nblk = blockIdx.y;
    int kyx0 = blockIdx.z * nkyx;
    int t = threadIdx.x;
    int lane = t & 63, wid = t >> 6;
    int swz = ((t & 3) ^ ((t >> 3) & 3)) * 8;
    int icsrc = swz;
    long bsrc = (t >> 2) * 32 + swz;

    long base0, base1;
    {
        int m = mblk * 128 + (t >> 2);
        int b = m / HWout; int rem = m - b * HWout;
        int oyy = rem / Wout; int oxx = rem - oyy * Wout;
        base0 = (long)b * imgStride + (long)(2 * oyy * Win + 2 * oxx) * 256;
        m += 64;
        b = m / HWout; rem = m - b * HWout;
        oyy = rem / Wout; oxx = rem - oyy * Wout;
        base1 = (long)b * imgStride + (long)(2 * oyy * Win + 2 * oxx) * 256;
    }

    f32x4 acc[4][4];
#pragma unroll
    for (int i = 0; i < 4; ++i)
#pragma unroll
        for (int j2 = 0; j2 < 4; ++j2) acc[i][j2] = (f32x4){0.f, 0.f, 0.f, 0.f};

    int wr = wid >> 1, wc = wid & 1;
    int slot8 = (((lane >> 4) ^ ((lane >> 1) & 3))) * 8;
    int a_off = ((wr * 64 + (lane & 15)) * 32 + slot8) * 2;
    int b_off = ((wc * 64 + (lane & 15)) * 32 + slot8) * 2;

    auto stage = [&](int s, int buf) {
        int kyx = kyx0 + (s >> 3);
        int icg = s & 7;
        int ky = kyx / 9, kx = kyx - ky * 9;
        long offA = (long)(ky * Win + kx) * 256 + icg * 32 + icsrc;
        long btb = (long)((kyx * 8 + icg) * 2 + nblk) * 4096 + bsrc;
        char* a0 = (char*)Ald + buf * 8192 + wid * 1024;
        char* b0 = (char*)Bld + buf * 8192 + wid * 1024;
        gload16(in + base0 + offA, a0);
        gload16(in + base1 + offA, a0 + 4096);
        gload16(wp + btb, b0);
        gload16(wp + btb + 2048, b0 + 4096);
    };

    int nsteps = nkyx * 8;
    stage(0, 0);
    stage(1, 1);
    stage(2, 2);
    int cur = 0;
    for (int s = 0; s < nsteps; ++s) {
        int rem = nsteps - 1 - s;
        if (rem >= 2) {
            asm volatile("s_waitcnt vmcnt(8)" ::: "memory");
        } else if (rem == 1) {
            asm volatile("s_waitcnt vmcnt(4)" ::: "memory");
        } else {
            asm volatile("s_waitcnt vmcnt(0)" ::: "memory");
        }
        __builtin_amdgcn_s_barrier();
        __builtin_amdgcn_sched_barrier(0);
        const char* Ac = (const char*)Ald + cur * 8192;
        const char* Bc = (const char*)Bld + cur * 8192;
        bf16x8 af[4], bfr[4];
#pragma unroll
        for (int i = 0; i < 4; ++i) af[i] = *(const bf16x8*)(Ac + a_off + i * 1024);
#pragma unroll
        for (int i = 0; i < 4; ++i) bfr[i] = *(const bf16x8*)(Bc + b_off + i * 1024);
#pragma unroll
        for (int mi = 0; mi < 4; ++mi)
#pragma unroll
            for (int ni = 0; ni < 4; ++ni)
                acc[mi][ni] = __builtin_amdgcn_mfma_f32_16x16x32_bf16(af[mi], bfr[ni], acc[mi][ni], 0, 0, 0);
        if (s + 3 < nsteps) {
            asm volatile("s_waitcnt lgkmcnt(0)" ::: "memory");
            __builtin_amdgcn_s_barrier();
            stage(s + 3, cur);
        }
        cur = (cur == 2) ? 0 : cur + 1;
    }

    int colbase = nblk * 128 + wc * 64 + (lane & 15);
    long mrowbase = (long)mblk * 128 + wr * 64 + (lane >> 4) * 4;
    if (mode == 0) {
#pragma unroll
        for (int mi = 0; mi < 4; ++mi) {
#pragma unroll
            for (int ni = 0; ni < 4; ++ni) {
                int col = colbase + ni * 16;
                float bs = bias[col];
#pragma unroll
                for (int r = 0; r < 4; ++r) {
                    long mrow = mrowbase + mi * 16 + r;
                    float v = acc[mi][ni][r] + bs;
                    v = v > 0.f ? v : 0.f;
                    out[mrow * 256 + col] = __float2bfloat16(v);
                }
            }
        }
    } else {
        float* pp = part + (long)blockIdx.z * Mtot * 256;
#pragma unroll
        for (int mi = 0; mi < 4; ++mi) {
#pragma unroll
            for (int ni = 0; ni < 4; ++ni) {
                int col = colbase + ni * 16;
#pragma unroll
                for (int r = 0; r < 4; ++r) {
                    long mrow = mrowbase + mi * 16 + r;
                    pp[mrow * 256 + col] = acc[mi][ni][r];
                }
            }
        }
    }
}

// ---------------- split-K reduce: sum 9 partials + bias + relu -> bf16 NHWC ----------------
__global__ __launch_bounds__(256) void reduce_parts_kernel(const float* __restrict__ part,
                                                           const float* __restrict__ bias,
                                                           __hip_bfloat16* __restrict__ out) {
    int idx = blockIdx.x * 256 + threadIdx.x;  // 4608*256
    float s = 0.f;
#pragma unroll
    for (int p = 0; p < 9; ++p) s += part[(long)p * 1179648 + idx];
    s += bias[idx & 255];
    s = s > 0.f ? s : 0.f;
    out[idx] = __float2bfloat16(s);
}

// ---------------- primary capsule squash: NHWC bf16 -> uT f32 [1152 i][128 b][8 d] ----------------
__global__ __launch_bounds__(256) void squash_caps_kernel(const __hip_bfloat16* __restrict__ c3,
                                                          float* __restrict__ uT) {
    int g = blockIdx.x * 256 + threadIdx.x;  // 147456 = 1152*128, i-major
    int i = g >> 7, b = g & 127;
    float val[8];
    float sn = 0.f;
#pragma unroll
    for (int d = 0; d < 8; ++d) {
        int flat = i * 8 + d;
        int c = flat / 36; int rem = flat - c * 36;
        int y = rem / 6; int xx = rem - y * 6;
        float vv = __bfloat162float(c3[((b * 6 + y) * 6 + xx) * 256 + c]);
        val[d] = vv;
        sn += vv * vv;
    }
    float sc = (sn / (1.f + sn)) / sqrtf(sn + 1e-8f);
#pragma unroll
    for (int d = 0; d < 8; ++d) uT[(long)g * 8 + d] = val[d] * sc;  // contiguous 32B/thread
}

// ---------------- u_hat[b,j,i,o] = sum_d uT[i,b,d] * W[j,i,d,o]  (vectorized LDS, conflict-free) ----------------
__global__ __launch_bounds__(256) void uhat_kernel(const float* __restrict__ uT,
                                                   const float* __restrict__ Wd,
                                                   __hip_bfloat16* __restrict__ uhat) {
    __shared__ float Wl2[1600];  // [jo=160][10]: 8 d-values + 2 pad (40B stride -> conflict-free b64)
    __shared__ float ul[1024];   // [b=128][8]   (32B stride -> b128 broadcast)
    int i = blockIdx.x, t = threadIdx.x;
    for (int idx = t; idx < 1280; idx += 256) {
        int j = idx >> 7, rest = idx & 127;
        int d = rest >> 4, o = rest & 15;
        Wl2[(j * 16 + o) * 10 + d] = Wd[((long)j * 1152 + i) * 128 + rest];
    }
    {
        const float4* usrc = (const float4*)(uT + (long)i * 1024);
        float4* ud = (float4*)ul;
        ud[t] = usrc[t];  // 256 float4 = whole [128][8]
    }
    __syncthreads();
    for (int rr = 0; rr < 80; ++rr) {
        int idx = rr * 256 + t;
        int b = idx / 160; int jo = idx - b * 160;
        const float* up = &ul[b * 8];
        const float* wq = &Wl2[jo * 10];
        float a = 0.f;
#pragma unroll
        for (int d = 0; d < 8; ++d) a += up[d] * wq[d];
        int j = jo >> 4, o = jo & 15;
        uhat[(((long)b * 10 + j) * 1152 + i) * 16 + o] = __float2bfloat16(a);
    }
}

// ---------------- fused dynamic routing per (b,j): 3 iterations in LDS ----------------
__global__ __launch_bounds__(256) void routing_kernel(const __hip_bfloat16* __restrict__ uhat,
                                                      const float* __restrict__ bdig,
                                                      float* __restrict__ vout,
                                                      float* __restrict__ vws) {
    __shared__ __hip_bfloat16 uh[1152 * 16];  // 36864B
    __shared__ float barr[1152];
    __shared__ float red[16];
    __shared__ float accb[16 * 256];          // 16KB
    __shared__ float svec[16];
    __shared__ float vsc[16];
    int bid = blockIdx.x;  // b*10 + j
    int j = bid % 10;
    int t = threadIdx.x;
    int wid = t >> 6;
    const uint4* srcp = (const uint4*)(uhat + (long)bid * 18432);
    uint4* dstp = (uint4*)uh;
    for (int idx = t; idx < 2304; idx += 256) dstp[idx] = srcp[idx];
    for (int idx = t; idx < 1152; idx += 256) barr[idx] = 0.f;
    __syncthreads();
    for (int it = 0; it < 3; ++it) {
        float lm = -1e30f;
        for (int i = t; i < 1152; i += 256) lm = fmaxf(lm, barr[i]);
#pragma unroll
        for (int m2 = 32; m2; m2 >>= 1) lm = fmaxf(lm, __shfl_xor(lm, m2));
        if ((t & 63) == 0) red[wid] = lm;
        __syncthreads();
        float mx = fmaxf(fmaxf(red[0], red[1]), fmaxf(red[2], red[3]));
        float le = 0.f;
        float a16[16];
#pragma unroll
        for (int o = 0; o < 16; ++o) a16[o] = 0.f;
        for (int i = t; i < 1152; i += 256) {
            float e = __expf(barr[i] - mx);
            le += e;
            const uint4* up = (const uint4*)(uh + i * 16);
            union { uint4 q; unsigned short s[8]; } U0, U1;
            U0.q = up[0]; U1.q = up[1];
#pragma unroll
            for (int o = 0; o < 8; ++o) a16[o] += e * bfu(U0.s[o]);
#pragma unroll
            for (int o = 0; o < 8; ++o) a16[8 + o] += e * bfu(U1.s[o]);
        }
#pragma unroll
        for (int m2 = 32; m2; m2 >>= 1) le += __shfl_xor(le, m2);
        if ((t & 63) == 0) red[4 + wid] = le;
#pragma unroll
        for (int o = 0; o < 16; ++o) accb[o * 256 + t] = a16[o];
        __syncthreads();
        float sume = red[4] + red[5] + red[6] + red[7];
        int g = t >> 4, tin = t & 15;
        float s = 0.f;
#pragma unroll
        for (int k = 0; k < 16; ++k) s += accb[g * 256 + tin + 16 * k];
#pragma unroll
        for (int m2 = 8; m2; m2 >>= 1) s += __shfl_xor(s, m2);
        if (tin == 0) svec[g] = s / sume + bdig[j * 16 + g];
        __syncthreads();
        if (t < 16) {
            float sv = svec[t];
            float sn = sv * sv;
#pragma unroll
            for (int m2 = 8; m2; m2 >>= 1) sn += __shfl_xor(sn, m2);
            float sc = (sn / (1.f + sn)) / sqrtf(sn + 1e-8f);
            float v = sv * sc;
            vsc[t] = v;
            if (it == 2) { vout[bid * 16 + t] = v; vws[bid * 16 + t] = v; }
        }
        __syncthreads();
        if (it < 2) {
            for (int i = t; i < 1152; i += 256) {
                const uint4* up = (const uint4*)(uh + i * 16);
                union { uint4 q; unsigned short s[8]; } U0, U1;
                U0.q = up[0]; U1.q = up[1];
                float dot = 0.f;
#pragma unroll
                for (int o = 0; o < 8; ++o) dot += vsc[o] * bfu(U0.s[o]);
#pragma unroll
                for (int o = 0; o < 8; ++o) dot += vsc[8 + o] * bfu(U1.s[o]);
                barr[i] += dot;
            }
            __syncthreads();
        }
    }
}

// ---------------- reconstruction GEMM: out[128,N] = act(A[128,K] x W[K,N] + bias) ----------------
__global__ __launch_bounds__(256) void rec_gemm_kernel(const float* __restrict__ A,
                                                       const float* __restrict__ W,
                                                       const float* __restrict__ bias,
                                                       float* __restrict__ out,
                                                       int K, int N, int act) {
    __shared__ float As[32 * 64];
    int n0 = blockIdx.x * 64;
    int bch = blockIdx.y * 32;
    int t = threadIdx.x;
    int n_l = t & 63, bh = t >> 6;
    float acc[8];
#pragma unroll
    for (int i = 0; i < 8; ++i) acc[i] = 0.f;
    for (int k0 = 0; k0 < K; k0 += 64) {
        int kc = K - k0;
        if (kc > 64) kc = 64;
        __syncthreads();
        for (int idx = t; idx < 2048; idx += 256) {
            int bb = idx >> 6, kk = idx & 63;
            if (kk < kc) As[idx] = A[(long)(bch + bb) * K + k0 + kk];
        }
        __syncthreads();
        const float* Wp = W + (long)k0 * N + n0 + n_l;
        if (kc == 64) {
#pragma unroll 8
            for (int kk = 0; kk < 64; ++kk) {
                float wv = Wp[(long)kk * N];
#pragma unroll
                for (int bb = 0; bb < 8; ++bb) acc[bb] += As[(bh * 8 + bb) * 64 + kk] * wv;
            }
        } else {
            for (int kk = 0; kk < kc; ++kk) {
                float wv = Wp[(long)kk * N];
#pragma unroll
                for (int bb = 0; bb < 8; ++bb) acc[bb] += As[(bh * 8 + bb) * 64 + kk] * wv;
            }
        }
    }
    float bs = bias[n0 + n_l];
    for (int bb = 0; bb < 8; ++bb) {
        float x = acc[bb] + bs;
        float r;
        if (act == 0) r = x > 0.f ? x : 0.f;
        else r = 1.f / (1.f + __expf(-x));
        out[(long)(bch + bh * 8 + bb) * N + n0 + n_l] = r;
    }
}

extern "C" void kernel_launch(void* const* d_in, const int* in_sizes, int n_in,
                              void* d_out, int out_size, void* d_ws, size_t ws_size,
                              hipStream_t stream) {
    const float* x   = (const float*)d_in[0];
    const float* c1w = (const float*)d_in[1];
    const float* c1b = (const float*)d_in[2];
    const float* c2w = (const float*)d_in[3];
    const float* c2b = (const float*)d_in[4];
    const float* pw  = (const float*)d_in[5];
    const float* pb  = (const float*)d_in[6];
    const float* Wd  = (const float*)d_in[7];
    const float* bd  = (const float*)d_in[8];
    const float* rw1 = (const float*)d_in[9];
    const float* rb1 = (const float*)d_in[10];
    const float* rw2 = (const float*)d_in[11];
    const float* rb2 = (const float*)d_in[12];
    const float* rw3 = (const float*)d_in[13];
    const float* rb3 = (const float*)d_in[14];
    float* outp = (float*)d_out;

    char* ws = (char*)d_ws;
    size_t off = 0;
    auto alloc = [&](size_t bytes) {
        char* p = ws + off;
        off += (bytes + 255) & ~(size_t)255;
        return p;
    };
    __hip_bfloat16* c1out = (__hip_bfloat16*)alloc(150994944UL);  // [128][48][48][256] bf16
    __hip_bfloat16* c2out = (__hip_bfloat16*)alloc(26214400UL);   // [128][20][20][256]
    __hip_bfloat16* c3out = (__hip_bfloat16*)alloc(2359296UL);    // [128][6][6][256]
    __hip_bfloat16* w2p   = (__hip_bfloat16*)alloc(10616832UL);
    __hip_bfloat16* w3p   = (__hip_bfloat16*)alloc(10616832UL);
    float* uT    = (float*)alloc(4718592UL);    // [1152][128][8] f32
    __hip_bfloat16* uhat = (__hip_bfloat16*)alloc(47185920UL);  // [128][10][1152][16] bf16
    float* vws   = (float*)alloc(81920UL);      // [128][160]
    float* rec1  = (float*)alloc(262144UL);     // [128][512]
    float* rec2  = (float*)alloc(524288UL);     // [128][1024]

    // conv3 split-K partials [9][4608][256] f32 = 42.5MB alias the (later-written) uhat buffer
    float* c3part = (float*)uhat;

    prep_w_kernel<<<1024, 256, 0, stream>>>(c2w, pw, w2p, w3p);
    conv1_kernel<<<dim3(48, 128), 256, 0, stream>>>(x, c1w, c1b, c1out);
    conv2_img_kernel<<<256, 512, 0, stream>>>(c1out, w2p, c2b, c2out);
    conv_mfma_kernel<<<dim3(36, 2, 9), 256, 0, stream>>>(c2out, w3p, pb, c3out, c3part,
                                                         20, 20 * 20 * 256, 36, 6, 9, 4608, 1);
    reduce_parts_kernel<<<4608, 256, 0, stream>>>(c3part, pb, c3out);
    squash_caps_kernel<<<576, 256, 0, stream>>>(c3out, uT);
    uhat_kernel<<<1152, 256, 0, stream>>>(uT, Wd, uhat);
    routing_kernel<<<1280, 256, 0, stream>>>(uhat, bd, outp, vws);
    rec_gemm_kernel<<<dim3(8, 4), 256, 0, stream>>>(vws, rw1, rb1, rec1, 160, 512, 0);
    rec_gemm_kernel<<<dim3(16, 4), 256, 0, stream>>>(rec1, rw2, rb2, rec2, 512, 1024, 0);
    rec_gemm_kernel<<<dim3(49, 4), 256, 0, stream>>>(rec2, rw3, rb3, outp + 20480, 1024, 3136, 1);
}

// Round 11
// 1470.917 us; speedup vs baseline: 1.0100x; 1.0100x over previous
//
#include <hip/hip_runtime.h>
#include <hip/hip_bf16.h>

typedef float f32x4 __attribute__((ext_vector_type(4)));
typedef __bf16 bf16x8 __attribute__((ext_vector_type(8)));

#define AS1 __attribute__((address_space(1)))
#define AS3 __attribute__((address_space(3)))

__device__ __forceinline__ void gload16(const void* g, void* l) {
    __builtin_amdgcn_global_load_lds((AS1 unsigned int*)g, (AS3 unsigned int*)l, 16, 0, 0);
}

__device__ __forceinline__ float bfu(unsigned short u) {
    return __uint_as_float((unsigned)u << 16);
}

// ---------------- weight prep: conv2/conv3 OIHW f32 -> [kyx][icg][nblk][oc128][ic32] bf16;
// block 1024 additionally transposes c1w [256][81] -> c1wT [81][256] for coalesced conv1 loads ----------------
__global__ __launch_bounds__(256) void prep_w_kernel(const float* __restrict__ wA,
                                                     const float* __restrict__ wB,
                                                     __hip_bfloat16* __restrict__ wpA,
                                                     __hip_bfloat16* __restrict__ wpB,
                                                     const float* __restrict__ c1w,
                                                     float* __restrict__ c1wT) {
    int bid = blockIdx.x;
    int t = threadIdx.x;
    if (bid == 1024) {
        float tmp[81];
#pragma unroll
        for (int k = 0; k < 81; ++k) tmp[k] = c1w[t * 81 + k];
#pragma unroll
        for (int k = 0; k < 81; ++k) c1wT[k * 256 + t] = tmp[k];
        return;
    }
    __shared__ float wl[4 * 32 * 81];  // [o][i][kyx]
    const float* w = (bid < 512) ? wA : wB;
    __hip_bfloat16* wp = (bid < 512) ? wpA : wpB;
    bid &= 511;
    int icg = bid & 7;
    int oc4 = (bid >> 3) & 31;
    int nblk = bid >> 8;
    int ocg0 = nblk * 128 + oc4 * 4;
    int ic0 = icg * 32;
    for (int f = t; f < 4 * 2592; f += 256) {
        int o = f / 2592;
        int rest = f - o * 2592;  // i*81 + kyx
        wl[f] = w[(ocg0 + o) * 20736 + ic0 * 81 + rest];
    }
    __syncthreads();
    for (int idx = t; idx < 81 * 128; idx += 256) {
        int kyx = idx >> 7;
        int o = (idx >> 5) & 3;
        int i = idx & 31;
        long dst = (long)(((kyx * 8 + icg) * 2 + nblk) * 128 + (oc4 * 4 + o)) * 32 + i;
        wp[dst] = __float2bfloat16(wl[o * 2592 + i * 81 + kyx]);
    }
}

// ---------------- conv1: 1->256ch 9x9 s1, f32 compute, weights preloaded COALESCED from c1wT ----------------
__global__ __launch_bounds__(256) void conv1_kernel(const float* __restrict__ x,
                                                    const float* __restrict__ wT,
                                                    const float* __restrict__ bias,
                                                    __hip_bfloat16* __restrict__ out) {
    __shared__ float rowb[504];  // 9 rows x 56
    int oy = blockIdx.x;  // 0..47
    int b = blockIdx.y;   // 0..127
    int t = threadIdx.x;  // = oc
    const float* src = x + b * 3136 + oy * 56;
    for (int i = t; i < 504; i += 256) rowb[i] = src[i];
    float w81[81];
#pragma unroll
    for (int k = 0; k < 81; ++k) w81[k] = wT[k * 256 + t];  // coalesced 256B/wave, L2-hot
    __syncthreads();
    float bs = bias[t];
    __hip_bfloat16* op = out + ((b * 48 + oy) * 48) * 256 + t;
    for (int p = 0; p < 3; ++p) {
        int ox0 = p * 16;
        float acc[16];
#pragma unroll
        for (int i = 0; i < 16; ++i) acc[i] = 0.f;
#pragma unroll
        for (int ky = 0; ky < 9; ++ky) {
            float r[24];
#pragma unroll
            for (int i = 0; i < 24; ++i) r[i] = rowb[ky * 56 + ox0 + i];
#pragma unroll
            for (int kx = 0; kx < 9; ++kx) {
                float wv = w81[ky * 9 + kx];
#pragma unroll
                for (int ox = 0; ox < 16; ++ox) acc[ox] = fmaf(wv, r[ox + kx], acc[ox]);
            }
        }
#pragma unroll
        for (int ox = 0; ox < 16; ++ox) {
            float v = acc[ox] + bs;
            v = v > 0.f ? v : 0.f;
            op[(ox0 + ox) * 256] = __float2bfloat16(v);
        }
    }
}

// ---------------- conv2: one image/block, LDS-resident im2col slice, barrier-free K-loop,
// register-double-buffered A-fragments (prefetch d=1), B double-buffer (per-icg reset),
// s_sleep wave skew to anti-correlate co-resident waves. ----------------
__global__ __launch_bounds__(512, 2) void conv2_img_kernel(const __hip_bfloat16* __restrict__ in,
                                                           const __hip_bfloat16* __restrict__ wp,
                                                           const float* __restrict__ bias,
                                                           __hip_bfloat16* __restrict__ out) {
    __shared__ __hip_bfloat16 Ald[73728];   // 147456 B = [48][48][32] swizzled
    int bid = blockIdx.x;
    int wg = (bid & 7) * 32 + (bid >> 3);   // XCD-chunk: nblk pair lands on same XCD
    int b = wg >> 1, nblk = wg & 1;
    int t = threadIdx.x;
    int lane = t & 63, wid = t >> 6;
    int wr = wid >> 1, wc = wid & 1;        // 4 (M) x 2 (N) wave grid
    int ch8 = lane >> 4;

    const __hip_bfloat16* imgbase = in + (long)b * (48 * 48 * 256);
    const __hip_bfloat16* wpn = wp + (long)nblk * 4096 + (wc * 64 + (lane & 15)) * 32 + ch8 * 8;

    int qbase[7];
#pragma unroll
    for (int mi = 0; mi < 7; ++mi) {
        int ml = wr * 96 + mi * 16 + (lane & 15);
        int oy = ml / 20, ox = ml - oy * 20;
        qbase[mi] = ((2 * oy) * 48 + 2 * ox) * 4 + ch8;
    }

    f32x4 acc[7][4];
#pragma unroll
    for (int i = 0; i < 7; ++i)
#pragma unroll
        for (int j = 0; j < 4; ++j) acc[i][j] = (f32x4){0.f, 0.f, 0.f, 0.f};

    auto stageA = [&](int icg) {
#pragma unroll
        for (int c = 0; c < 3; ++c) {
            uint4 v[6];
#pragma unroll
            for (int j = 0; j < 6; ++j) {
                int gi = t + (c * 6 + j) * 512;
                int lrow = gi >> 2;
                int iy = lrow / 48;
                int col = lrow - iy * 48;
                if (iy > 46) iy = 46;  // row 47 pad, never read
                v[j] = *(const uint4*)(imgbase + (iy * 48 + col) * 256 + icg * 32 + (gi & 3) * 8);
            }
#pragma unroll
            for (int j = 0; j < 6; ++j) {
                int gi = t + (c * 6 + j) * 512;
                int phys = gi ^ ((gi >> 3) & 7);
                *(uint4*)((char*)Ald + phys * 16) = v[j];
            }
        }
    };

    bf16x8 af_e[7], af_o[7], Be[4], Bo[4];
    int pf_kdelta = 0, pf_kx = 0, pf_ky = 0;
    auto prefA = [&](bf16x8* af) {
#pragma unroll
        for (int mi = 0; mi < 7; ++mi) {
            int q = qbase[mi] + pf_kdelta;
            int phys = q ^ ((q >> 3) & 7);
            af[mi] = *(const bf16x8*)((const char*)Ald + phys * 16);
        }
        ++pf_kx; pf_kdelta += 4;
        if (pf_kx == 9) { pf_kx = 0; ++pf_ky; pf_kdelta = pf_ky * 192; }
    };
    auto domfma = [&](bf16x8* af, bf16x8* bf) {
        __builtin_amdgcn_s_setprio(1);
#pragma unroll
        for (int mi = 0; mi < 7; ++mi)
#pragma unroll
            for (int ni = 0; ni < 4; ++ni)
                acc[mi][ni] = __builtin_amdgcn_mfma_f32_16x16x32_bf16(af[mi], bf[ni], acc[mi][ni], 0, 0, 0);
        __builtin_amdgcn_s_setprio(0);
    };

    for (int icg = 0; icg < 8; ++icg) {
        const __hip_bfloat16* wpi = wpn + (long)icg * 8192;
        auto loadB = [&](bf16x8* dst, int kyx) {
            const __hip_bfloat16* p = wpi + (long)kyx * 65536;
#pragma unroll
            for (int ni = 0; ni < 4; ++ni) dst[ni] = *(const bf16x8*)(p + ni * 512);
        };
        if (icg) __builtin_amdgcn_s_barrier();   // all waves done reading old A
        loadB(Be, 0);
        loadB(Bo, 1);
        stageA(icg);
        asm volatile("s_waitcnt lgkmcnt(0)" ::: "memory");
        __builtin_amdgcn_s_barrier();
        if (wid >= 4) asm volatile("s_sleep 4");   // de-phase co-resident waves

        pf_kx = 0; pf_ky = 0; pf_kdelta = 0;
        prefA(af_e);                                // step 0 fragments
        for (int it2 = 0; it2 < 40; ++it2) {
            prefA(af_o);
            domfma(af_e, Be);
            loadB(Be, 2 * it2 + 2);
            prefA(af_e);
            domfma(af_o, Bo);
            loadB(Bo, 2 * it2 + 3);   // kyx 81,82 read harmless garbage past tile (never used)
        }
        domfma(af_e, Be);                           // step 80
    }

    int colbase = nblk * 128 + wc * 64 + (lane & 15);
#pragma unroll
    for (int mi = 0; mi < 7; ++mi) {
#pragma unroll
        for (int ni = 0; ni < 4; ++ni) {
            int col = colbase + ni * 16;
            float bs = bias[col];
#pragma unroll
            for (int r = 0; r < 4; ++r) {
                int ml = wr * 96 + mi * 16 + (lane >> 4) * 4 + r;
                float v = acc[mi][ni][r] + bs;
                v = v > 0.f ? v : 0.f;
                out[((long)b * 400 + ml) * 256 + col] = __float2bfloat16(v);
            }
        }
    }
}

// ---------------- conv3: implicit-GEMM 128x128 (split-K), ring-3, counted vmcnt ----------------
__global__ __launch_bounds__(256) void conv_mfma_kernel(const __hip_bfloat16* __restrict__ in,
                                                        const __hip_bfloat16* __restrict__ wp,
                                                        const float* __restrict__ bias,
                                                        __hip_bfloat16* __restrict__ out,
                                                        float* __restrict__ part,
                                                        int Win, int imgStride, int HWout, int Wout,
                                                        int nkyx, int Mtot, int mode) {
    __shared__ __hip_bfloat16 Ald[3 * 4096];
    __shared__ __hip_bfloat16 Bld[3 * 4096];
    int mblk = blockIdx.x, nblk = blockIdx.y;
    int kyx0 = blockIdx.z * nkyx;
    int t = threadIdx.x;
    int lane = t & 63, wid = t >> 6;
    int swz = ((t & 3) ^ ((t >> 3) & 3)) * 8;
    int icsrc = swz;
    long bsrc = (t >> 2) * 32 + swz;

    long base0, base1;
    {
        int m = mblk * 128 + (t >> 2);
        int b = m / HWout; int rem = m - b * HWout;
        int oyy = rem / Wout; int oxx = rem - oyy * Wout;
        base0 = (long)b * imgStride + (long)(2 * oyy * Win + 2 * oxx) * 256;
        m += 64;
        b = m / HWout; rem = m - b * HWout;
        oyy = rem / Wout; oxx = rem - oyy * Wout;
        base1 = (long)b * imgStride + (long)(2 * oyy * Win + 2 * oxx) * 256;
    }

    f32x4 acc[4][4];
#pragma unroll
    for (int i = 0; i < 4; ++i)
#pragma unroll
        for (int j2 = 0; j2 < 4; ++j2) acc[i][j2] = (f32x4){0.f, 0.f, 0.f, 0.f};

    int wr = wid >> 1, wc = wid & 1;
    int slot8 = (((lane >> 4) ^ ((lane >> 1) & 3))) * 8;
    int a_off = ((wr * 64 + (lane & 15)) * 32 + slot8) * 2;
    int b_off = ((wc * 64 + (lane & 15)) * 32 + slot8) * 2;

    auto stage = [&](int s, int buf) {
        int kyx = kyx0 + (s >> 3);
        int icg = s & 7;
        int ky = kyx / 9, kx = kyx - ky * 9;
        long offA = (long)(ky * Win + kx) * 256 + icg * 32 + icsrc;
        long btb = (long)((kyx * 8 + icg) * 2 + nblk) * 4096 + bsrc;
        char* a0 = (char*)Ald + buf * 8192 + wid * 1024;
        char* b0 = (char*)Bld + buf * 8192 + wid * 1024;
        gload16(in + base0 + offA, a0);
        gload16(in + base1 + offA, a0 + 4096);
        gload16(wp + btb, b0);
        gload16(wp + btb + 2048, b0 + 4096);
    };

    int nsteps = nkyx * 8;
    stage(0, 0);
    stage(1, 1);
    stage(2, 2);
    int cur = 0;
    for (int s = 0; s < nsteps; ++s) {
        int rem = nsteps - 1 - s;
        if (rem >= 2) {
            asm volatile("s_waitcnt vmcnt(8)" ::: "memory");
        } else if (rem == 1) {
            asm volatile("s_waitcnt vmcnt(4)" ::: "memory");
        } else {
            asm volatile("s_waitcnt vmcnt(0)" ::: "memory");
        }
        __builtin_amdgcn_s_barrier();
        __builtin_amdgcn_sched_barrier(0);
        const char* Ac = (const char*)Ald + cur * 8192;
        const char* Bc = (const char*)Bld + cur * 8192;
        bf16x8 af[4], bfr[4];
#pragma unroll
        for (int i = 0; i < 4; ++i) af[i] = *(const bf16x8*)(Ac + a_off + i * 1024);
#pragma unroll
        for (int i = 0; i < 4; ++i) bfr[i] = *(const bf16x8*)(Bc + b_off + i * 1024);
#pragma unroll
        for (int mi = 0; mi < 4; ++mi)
#pragma unroll
            for (int ni = 0; ni < 4; ++ni)
                acc[mi][ni] = __builtin_amdgcn_mfma_f32_16x16x32_bf16(af[mi], bfr[ni], acc[mi][ni], 0, 0, 0);
        if (s + 3 < nsteps) {
            asm volatile("s_waitcnt lgkmcnt(0)" ::: "memory");
            __builtin_amdgcn_s_barrier();
            stage(s + 3, cur);
        }
        cur = (cur == 2) ? 0 : cur + 1;
    }

    int colbase = nblk * 128 + wc * 64 + (lane & 15);
    long mrowbase = (long)mblk * 128 + wr * 64 + (lane >> 4) * 4;
    if (mode == 0) {
#pragma unroll
        for (int mi = 0; mi < 4; ++mi) {
#pragma unroll
            for (int ni = 0; ni < 4; ++ni) {
                int col = colbase + ni * 16;
                float bs = bias[col];
#pragma unroll
                for (int r = 0; r < 4; ++r) {
                    long mrow = mrowbase + mi * 16 + r;
                    float v = acc[mi][ni][r] + bs;
                    v = v > 0.f ? v : 0.f;
                    out[mrow * 256 + col] = __float2bfloat16(v);
                }
            }
        }
    } else {
        float* pp = part + (long)blockIdx.z * Mtot * 256;
#pragma unroll
        for (int mi = 0; mi < 4; ++mi) {
#pragma unroll
            for (int ni = 0; ni < 4; ++ni) {
                int col = colbase + ni * 16;
#pragma unroll
                for (int r = 0; r < 4; ++r) {
                    long mrow = mrowbase + mi * 16 + r;
                    pp[mrow * 256 + col] = acc[mi][ni][r];
                }
            }
        }
    }
}

// ---------------- split-K reduce: sum 9 partials + bias + relu -> bf16 NHWC ----------------
__global__ __launch_bounds__(256) void reduce_parts_kernel(const float* __restrict__ part,
                                                           const float* __restrict__ bias,
                                                           __hip_bfloat16* __restrict__ out) {
    int idx = blockIdx.x * 256 + threadIdx.x;  // 4608*256
    float s = 0.f;
#pragma unroll
    for (int p = 0; p < 9; ++p) s += part[(long)p * 1179648 + idx];
    s += bias[idx & 255];
    s = s > 0.f ? s : 0.f;
    out[idx] = __float2bfloat16(s);
}

// ---------------- primary capsule squash: NHWC bf16 -> uT f32 [1152 i][128 b][8 d] ----------------
__global__ __launch_bounds__(256) void squash_caps_kernel(const __hip_bfloat16* __restrict__ c3,
                                                          float* __restrict__ uT) {
    int g = blockIdx.x * 256 + threadIdx.x;  // 147456 = 1152*128, i-major
    int i = g >> 7, b = g & 127;
    float val[8];
    float sn = 0.f;
#pragma unroll
    for (int d = 0; d < 8; ++d) {
        int flat = i * 8 + d;
        int c = flat / 36; int rem = flat - c * 36;
        int y = rem / 6; int xx = rem - y * 6;
        float vv = __bfloat162float(c3[((b * 6 + y) * 6 + xx) * 256 + c]);
        val[d] = vv;
        sn += vv * vv;
    }
    float sc = (sn / (1.f + sn)) / sqrtf(sn + 1e-8f);
#pragma unroll
    for (int d = 0; d < 8; ++d) uT[(long)g * 8 + d] = val[d] * sc;  // contiguous 32B/thread
}

// ---------------- u_hat[b,j,i,o] = sum_d uT[i,b,d] * W[j,i,d,o]  (vectorized LDS, no div in loop) ----------------
__global__ __launch_bounds__(256) void uhat_kernel(const float* __restrict__ uT,
                                                   const float* __restrict__ Wd,
                                                   __hip_bfloat16* __restrict__ uhat) {
    __shared__ float Wl2[1600];  // [jo=160][10]: 8 d-values + 2 pad (40B stride -> conflict-free b64)
    __shared__ float ul[1024];   // [b=128][8]   (32B stride -> b128 broadcast)
    int i = blockIdx.x, t = threadIdx.x;
    for (int idx = t; idx < 1280; idx += 256) {
        int j = idx >> 7, rest = idx & 127;
        int d = rest >> 4, o = rest & 15;
        Wl2[(j * 16 + o) * 10 + d] = Wd[((long)j * 1152 + i) * 128 + rest];
    }
    {
        const float4* usrc = (const float4*)(uT + (long)i * 1024);
        float4* ud = (float4*)ul;
        ud[t] = usrc[t];  // 256 float4 = whole [128][8]
    }
    __syncthreads();
    int b = (t >= 160) ? 1 : 0;
    int jo = (t >= 160) ? t - 160 : t;
    for (int rr = 0; rr < 80; ++rr) {
        const float* up = &ul[b * 8];
        const float* wq = &Wl2[jo * 10];
        float a = 0.f;
#pragma unroll
        for (int d = 0; d < 8; ++d) a += up[d] * wq[d];
        int j = jo >> 4, o = jo & 15;
        uhat[(((long)b * 10 + j) * 1152 + i) * 16 + o] = __float2bfloat16(a);
        jo += 96; b += 1;
        if (jo >= 160) { jo -= 160; b += 1; }
    }
}

// ---------------- fused dynamic routing per (b,j): 3 iterations in LDS ----------------
__global__ __launch_bounds__(256) void routing_kernel(const __hip_bfloat16* __restrict__ uhat,
                                                      const float* __restrict__ bdig,
                                                      float* __restrict__ vout,
                                                      float* __restrict__ vws) {
    __shared__ __hip_bfloat16 uh[1152 * 16];  // 36864B
    __shared__ float barr[1152];
    __shared__ float red[16];
    __shared__ float accb[16 * 256];          // 16KB
    __shared__ float svec[16];
    __shared__ float vsc[16];
    int bid = blockIdx.x;  // b*10 + j
    int j = bid % 10;
    int t = threadIdx.x;
    int wid = t >> 6;
    const uint4* srcp = (const uint4*)(uhat + (long)bid * 18432);
    uint4* dstp = (uint4*)uh;
    for (int idx = t; idx < 2304; idx += 256) dstp[idx] = srcp[idx];
    for (int idx = t; idx < 1152; idx += 256) barr[idx] = 0.f;
    __syncthreads();
    for (int it = 0; it < 3; ++it) {
        float lm = -1e30f;
        for (int i = t; i < 1152; i += 256) lm = fmaxf(lm, barr[i]);
#pragma unroll
        for (int m2 = 32; m2; m2 >>= 1) lm = fmaxf(lm, __shfl_xor(lm, m2));
        if ((t & 63) == 0) red[wid] = lm;
        __syncthreads();
        float mx = fmaxf(fmaxf(red[0], red[1]), fmaxf(red[2], red[3]));
        float le = 0.f;
        float a16[16];
#pragma unroll
        for (int o = 0; o < 16; ++o) a16[o] = 0.f;
        for (int i = t; i < 1152; i += 256) {
            float e = __expf(barr[i] - mx);
            le += e;
            const uint4* up = (const uint4*)(uh + i * 16);
            union { uint4 q; unsigned short s[8]; } U0, U1;
            U0.q = up[0]; U1.q = up[1];
#pragma unroll
            for (int o = 0; o < 8; ++o) a16[o] += e * bfu(U0.s[o]);
#pragma unroll
            for (int o = 0; o < 8; ++o) a16[8 + o] += e * bfu(U1.s[o]);
        }
#pragma unroll
        for (int m2 = 32; m2; m2 >>= 1) le += __shfl_xor(le, m2);
        if ((t & 63) == 0) red[4 + wid] = le;
#pragma unroll
        for (int o = 0; o < 16; ++o) accb[o * 256 + t] = a16[o];
        __syncthreads();
        float sume = red[4] + red[5] + red[6] + red[7];
        int g = t >> 4, tin = t & 15;
        float s = 0.f;
#pragma unroll
        for (int k = 0; k < 16; ++k) s += accb[g * 256 + tin + 16 * k];
#pragma unroll
        for (int m2 = 8; m2; m2 >>= 1) s += __shfl_xor(s, m2);
        if (tin == 0) svec[g] = s / sume + bdig[j * 16 + g];
        __syncthreads();
        if (t < 16) {
            float sv = svec[t];
            float sn = sv * sv;
#pragma unroll
            for (int m2 = 8; m2; m2 >>= 1) sn += __shfl_xor(sn, m2);
            float sc = (sn / (1.f + sn)) / sqrtf(sn + 1e-8f);
            float v = sv * sc;
            vsc[t] = v;
            if (it == 2) { vout[bid * 16 + t] = v; vws[bid * 16 + t] = v; }
        }
        __syncthreads();
        if (it < 2) {
            for (int i = t; i < 1152; i += 256) {
                const uint4* up = (const uint4*)(uh + i * 16);
                union { uint4 q; unsigned short s[8]; } U0, U1;
                U0.q = up[0]; U1.q = up[1];
                float dot = 0.f;
#pragma unroll
                for (int o = 0; o < 8; ++o) dot += vsc[o] * bfu(U0.s[o]);
#pragma unroll
                for (int o = 0; o < 8; ++o) dot += vsc[8 + o] * bfu(U1.s[o]);
                barr[i] += dot;
            }
            __syncthreads();
        }
    }
}

// ---------------- reconstruction GEMM: out[128,N] = act(A[128,K] x W[K,N] + bias) ----------------
__global__ __launch_bounds__(256) void rec_gemm_kernel(const float* __restrict__ A,
                                                       const float* __restrict__ W,
                                                       const float* __restrict__ bias,
                                                       float* __restrict__ out,
                                                       int K, int N, int act) {
    __shared__ float As[32 * 64];
    int n0 = blockIdx.x * 64;
    int bch = blockIdx.y * 32;
    int t = threadIdx.x;
    int n_l = t & 63, bh = t >> 6;
    float acc[8];
#pragma unroll
    for (int i = 0; i < 8; ++i) acc[i] = 0.f;
    for (int k0 = 0; k0 < K; k0 += 64) {
        int kc = K - k0;
        if (kc > 64) kc = 64;
        __syncthreads();
        for (int idx = t; idx < 2048; idx += 256) {
            int bb = idx >> 6, kk = idx & 63;
            if (kk < kc) As[idx] = A[(long)(bch + bb) * K + k0 + kk];
        }
        __syncthreads();
        const float* Wp = W + (long)k0 * N + n0 + n_l;
        if (kc == 64) {
#pragma unroll 8
            for (int kk = 0; kk < 64; ++kk) {
                float wv = Wp[(long)kk * N];
#pragma unroll
                for (int bb = 0; bb < 8; ++bb) acc[bb] += As[(bh * 8 + bb) * 64 + kk] * wv;
            }
        } else {
            for (int kk = 0; kk < kc; ++kk) {
                float wv = Wp[(long)kk * N];
#pragma unroll
                for (int bb = 0; bb < 8; ++bb) acc[bb] += As[(bh * 8 + bb) * 64 + kk] * wv;
            }
        }
    }
    float bs = bias[n0 + n_l];
    for (int bb = 0; bb < 8; ++bb) {
        float x = acc[bb] + bs;
        float r;
        if (act == 0) r = x > 0.f ? x : 0.f;
        else r = 1.f / (1.f + __expf(-x));
        out[(long)(bch + bh * 8 + bb) * N + n0 + n_l] = r;
    }
}

extern "C" void kernel_launch(void* const* d_in, const int* in_sizes, int n_in,
                              void* d_out, int out_size, void* d_ws, size_t ws_size,
                              hipStream_t stream) {
    const float* x   = (const float*)d_in[0];
    const float* c1w = (const float*)d_in[1];
    const float* c1b = (const float*)d_in[2];
    const float* c2w = (const float*)d_in[3];
    const float* c2b = (const float*)d_in[4];
    const float* pw  = (const float*)d_in[5];
    const float* pb  = (const float*)d_in[6];
    const float* Wd  = (const float*)d_in[7];
    const float* bd  = (const float*)d_in[8];
    const float* rw1 = (const float*)d_in[9];
    const float* rb1 = (const float*)d_in[10];
    const float* rw2 = (const float*)d_in[11];
    const float* rb2 = (const float*)d_in[12];
    const float* rw3 = (const float*)d_in[13];
    const float* rb3 = (const float*)d_in[14];
    float* outp = (float*)d_out;

    char* ws = (char*)d_ws;
    size_t off = 0;
    auto alloc = [&](size_t bytes) {
        char* p = ws + off;
        off += (bytes + 255) & ~(size_t)255;
        return p;
    };
    __hip_bfloat16* c1out = (__hip_bfloat16*)alloc(150994944UL);  // [128][48][48][256] bf16
    __hip_bfloat16* c2out = (__hip_bfloat16*)alloc(26214400UL);   // [128][20][20][256]
    __hip_bfloat16* c3out = (__hip_bfloat16*)alloc(2359296UL);    // [128][6][6][256]
    __hip_bfloat16* w2p   = (__hip_bfloat16*)alloc(10616832UL);
    __hip_bfloat16* w3p   = (__hip_bfloat16*)alloc(10616832UL);
    float* c1wT  = (float*)alloc(82944UL);      // [81][256] f32
    float* uT    = (float*)alloc(4718592UL);    // [1152][128][8] f32
    __hip_bfloat16* uhat = (__hip_bfloat16*)alloc(47185920UL);  // [128][10][1152][16] bf16
    float* vws   = (float*)alloc(81920UL);      // [128][160]
    float* rec1  = (float*)alloc(262144UL);     // [128][512]
    float* rec2  = (float*)alloc(524288UL);     // [128][1024]

    // conv3 split-K partials [9][4608][256] f32 = 42.5MB alias the (later-written) uhat buffer
    float* c3part = (float*)uhat;

    prep_w_kernel<<<1025, 256, 0, stream>>>(c2w, pw, w2p, w3p, c1w, c1wT);
    conv1_kernel<<<dim3(48, 128), 256, 0, stream>>>(x, c1wT, c1b, c1out);
    conv2_img_kernel<<<256, 512, 0, stream>>>(c1out, w2p, c2b, c2out);
    conv_mfma_kernel<<<dim3(36, 2, 9), 256, 0, stream>>>(c2out, w3p, pb, c3out, c3part,
                                                         20, 20 * 20 * 256, 36, 6, 9, 4608, 1);
    reduce_parts_kernel<<<4608, 256, 0, stream>>>(c3part, pb, c3out);
    squash_caps_kernel<<<576, 256, 0, stream>>>(c3out, uT);
    uhat_kernel<<<1152, 256, 0, stream>>>(uT, Wd, uhat);
    routing_kernel<<<1280, 256, 0, stream>>>(uhat, bd, outp, vws);
    rec_gemm_kernel<<<dim3(8, 4), 256, 0, stream>>>(vws, rw1, rb1, rec1, 160, 512, 0);
    rec_gemm_kernel<<<dim3(16, 4), 256, 0, stream>>>(rec1, rw2, rb2, rec2, 512, 1024, 0);
    rec_gemm_kernel<<<dim3(49, 4), 256, 0, stream>>>(rec2, rw3, rb3, outp + 20480, 1024, 3136, 1);
}